// Round 2
// baseline (14772.725 us; speedup 1.0000x reference)
//
#include <hip/hip_runtime.h>
#include <hip/hip_bf16.h>

#define N_USER 60000
#define N_ITEM 120000
#define NTOT   180000
#define NNZ_ADJ 3600000
#define NNZ_UG   960000
#define NNZ_IG  1920000

typedef __hip_bfloat16 bf16;

// load float element i from input tensor of unknown dtype: flag=1 -> fp32, 0 -> bf16
__device__ __forceinline__ float ldf(const void* p, long i, int f) {
    return f ? ((const float*)p)[i] : __bfloat162float(((const bf16*)p)[i]);
}

// ---------------- dtype detector ----------------
// adj_vals = uniform(0,0.05): strictly non-negative. If stored bf16, every
// even-indexed 16-bit word is a valid bf16 with sign bit 0. If stored fp32,
// even-indexed 16-bit words are low mantissa halves (uniform) -> ~50% bit15 set.
__global__ void k_detect(const void* __restrict__ vals, int* __restrict__ flag) {
    if (threadIdx.x == 0 && blockIdx.x == 0) {
        const unsigned short* w = (const unsigned short*)vals;
        int cnt = 0;
        for (int i = 0; i < 512; i += 2) cnt += (w[i] >> 15) & 1;
        *flag = (cnt > 16) ? 1 : 0;
    }
}

// ---------------- cast user/item emb -> ego0 (fp32) ----------------
__global__ __launch_bounds__(256) void k_cast2f32(const void* __restrict__ ue,
                                                  const void* __restrict__ ie,
                                                  float* __restrict__ ego,
                                                  const int* __restrict__ flag) {
    int f = *flag;
    long i = (long)blockIdx.x * 256 + threadIdx.x;   // NTOT*64 = 11,520,000
    const long uN = (long)N_USER * 64;
    if (i < (long)NTOT * 64) {
        ego[i] = (i < uN) ? ldf(ue, i, f) : ldf(ie, i - uN, f);
    }
}

// ---------------- SpMM via atomics: out[rows[e],:] += vals[e] * x[cols[e],:] ----------------
__global__ __launch_bounds__(256) void k_spmm(const int* __restrict__ rows,
                                              const int* __restrict__ cols,
                                              const void* __restrict__ vals,
                                              const float* __restrict__ x,
                                              float* __restrict__ out, int nnz,
                                              const int* __restrict__ flag) {
    int f = *flag;
    int t = blockIdx.x * 256 + threadIdx.x;
    int e = t >> 4;          // 16 threads per nnz
    int p = t & 15;          // each handles 4 columns
    if (e < nnz) {
        int r = rows[e], c = cols[e];
        float v = ldf(vals, e, f);
        const float4 xv = *(const float4*)(x + (long)c * 64 + p * 4);
        float* o = out + (long)r * 64 + p * 4;
        atomicAdd(o + 0, v * xv.x);
        atomicAdd(o + 1, v * xv.y);
        atomicAdd(o + 2, v * xv.z);
        atomicAdd(o + 3, v * xv.w);
    }
}

// ---------------- Y[M,64] = act(X[M,64] @ W[64,64] + b) ----------------
// ACT: 1 = elu (f32 out), 2 = relu -> bf16 out (internal scratch)
template <int ACT>
__global__ __launch_bounds__(256) void k_gemm64(const float* __restrict__ X,
                                                const void* __restrict__ W,
                                                const void* __restrict__ b,
                                                void* __restrict__ Y, int M,
                                                const int* __restrict__ flag) {
    __shared__ float Wl[64][64];
    __shared__ float bl[64];
    int f = *flag;
    int tid = threadIdx.x;
    for (int i = tid; i < 4096; i += 256) Wl[i >> 6][i & 63] = ldf(W, i, f);
    if (tid < 64) bl[tid] = ldf(b, tid, f);
    __syncthreads();

    int r = blockIdx.x * 256 + tid;
    if (r >= M) return;
    const float* xr = X + (long)r * 64;

    float acc[64];
#pragma unroll
    for (int j = 0; j < 64; j++) acc[j] = bl[j];

    for (int k4 = 0; k4 < 64; k4 += 4) {
        float4 xv = *(const float4*)(xr + k4);
#pragma unroll
        for (int kk = 0; kk < 4; kk++) {
            float xs = (kk == 0) ? xv.x : (kk == 1) ? xv.y : (kk == 2) ? xv.z : xv.w;
#pragma unroll
            for (int j = 0; j < 64; j += 4) {
                float4 w4 = *(const float4*)&Wl[k4 + kk][j];
                acc[j + 0] += xs * w4.x;
                acc[j + 1] += xs * w4.y;
                acc[j + 2] += xs * w4.z;
                acc[j + 3] += xs * w4.w;
            }
        }
    }

    if (ACT == 2) {
        bf16* y = (bf16*)Y + (long)r * 64;
#pragma unroll
        for (int j = 0; j < 64; j++) y[j] = __float2bfloat16(fmaxf(acc[j], 0.0f));
    } else {
        float* y = (float*)Y + (long)r * 64;
#pragma unroll
        for (int j = 0; j < 64; j++) {
            float v = acc[j];
            y[j] = (v > 0.0f) ? v : (expf(v) - 1.0f);
        }
    }
}

// ---------------- fused NGCF layer transform ----------------
// Eout = leaky_relu( S@Wgc + bgc + (E*S)@Wbi + bbi , 0.2 )
// woff/boff are ELEMENT offsets (dtype-independent) selecting layer k.
__global__ __launch_bounds__(256) void k_layer(const float* __restrict__ S,
                                               const float* __restrict__ E,
                                               const void* __restrict__ Wgc,
                                               const void* __restrict__ bgc,
                                               const void* __restrict__ Wbi,
                                               const void* __restrict__ bbi,
                                               long woff, long boff,
                                               float* __restrict__ Eout, int M,
                                               const int* __restrict__ flag) {
    __shared__ float W1[64][64];
    __shared__ float W2[64][64];
    __shared__ float bl[64];
    int f = *flag;
    int tid = threadIdx.x;
    for (int i = tid; i < 4096; i += 256) {
        W1[i >> 6][i & 63] = ldf(Wgc, woff + i, f);
        W2[i >> 6][i & 63] = ldf(Wbi, woff + i, f);
    }
    if (tid < 64) bl[tid] = ldf(bgc, boff + tid, f) + ldf(bbi, boff + tid, f);
    __syncthreads();

    int r = blockIdx.x * 256 + tid;
    if (r >= M) return;
    const float* sr = S + (long)r * 64;
    const float* er = E + (long)r * 64;

    float acc[64];
#pragma unroll
    for (int j = 0; j < 64; j++) acc[j] = bl[j];

    for (int k4 = 0; k4 < 64; k4 += 4) {
        float4 sv = *(const float4*)(sr + k4);
        float4 ev = *(const float4*)(er + k4);
#pragma unroll
        for (int kk = 0; kk < 4; kk++) {
            float xs = (kk == 0) ? sv.x : (kk == 1) ? sv.y : (kk == 2) ? sv.z : sv.w;
            float xe = ((kk == 0) ? ev.x : (kk == 1) ? ev.y : (kk == 2) ? ev.z : ev.w) * xs;
#pragma unroll
            for (int j = 0; j < 64; j += 4) {
                float4 w1 = *(const float4*)&W1[k4 + kk][j];
                float4 w2 = *(const float4*)&W2[k4 + kk][j];
                acc[j + 0] += xs * w1.x + xe * w2.x;
                acc[j + 1] += xs * w1.y + xe * w2.y;
                acc[j + 2] += xs * w1.z + xe * w2.z;
                acc[j + 3] += xs * w1.w + xe * w2.w;
            }
        }
    }

    float* y = Eout + (long)r * 64;
#pragma unroll
    for (int j = 0; j < 64; j++) {
        float v = acc[j];
        y[j] = (v > 0.0f) ? v : 0.2f * v;
    }
}

// ---------------- row-wise l2 normalize, store bf16 (internal) ----------------
__global__ __launch_bounds__(256) void k_l2norm(const float* __restrict__ X,
                                                bf16* __restrict__ Y) {
    long g = (long)blockIdx.x * 256 + threadIdx.x;   // exactly NTOT*64 threads
    long row = g >> 6;
    int lane = threadIdx.x & 63;
    float v = X[row * 64 + lane];
    float ss = v * v;
#pragma unroll
    for (int d = 32; d >= 1; d >>= 1) ss += __shfl_xor(ss, d, 64);
    float sc = 1.0f / fmaxf(sqrtf(ss), 1e-12f);
    Y[row * 64 + lane] = __float2bfloat16(v * sc);
}

// ---------------- final gather into output ----------------
__global__ __launch_bounds__(64) void k_gather(const int* __restrict__ users,
                                               const int* __restrict__ pos,
                                               const int* __restrict__ neg,
                                               const void* __restrict__ ue,
                                               const void* __restrict__ ie,
                                               const bf16* __restrict__ n1,
                                               const bf16* __restrict__ n2,
                                               const bf16* __restrict__ n3,
                                               const bf16* __restrict__ uh,
                                               const bf16* __restrict__ ih,
                                               void* __restrict__ out,
                                               const int* __restrict__ flag) {
    int f = *flag;
    int b = blockIdx.x;           // 0..12287: [users | pos | neg] x 4096
    int which = b >> 12;
    int s = b & 4095;
    int lane = threadIdx.x;       // 64
    long ebase, nbase;
    const void* e0;
    const bf16* hh;
    if (which == 0) {
        int r = users[s];
        e0 = ue; ebase = (long)r * 64;
        hh = uh + (long)r * 64;
        nbase = (long)r * 64;
    } else {
        int r = (which == 1) ? pos[s] : neg[s];
        e0 = ie; ebase = (long)r * 64;
        hh = ih + (long)r * 64;
        nbase = (long)(N_USER + r) * 64;
    }
    float o0 = ldf(e0, ebase + lane, f);
    float o1 = __bfloat162float(n1[nbase + lane]);
    float o2 = __bfloat162float(n2[nbase + lane]);
    float o3 = __bfloat162float(n3[nbase + lane]);
    float o4 = __bfloat162float(hh[lane]);
    long ob = (long)b * 320;
    if (f) {
        float* o = (float*)out + ob;
        o[lane] = o0; o[64 + lane] = o1; o[128 + lane] = o2;
        o[192 + lane] = o3; o[256 + lane] = o4;
    } else {
        bf16* o = (bf16*)out + ob;
        o[lane]       = __float2bfloat16(o0);
        o[64 + lane]  = __float2bfloat16(o1);
        o[128 + lane] = __float2bfloat16(o2);
        o[192 + lane] = __float2bfloat16(o3);
        o[256 + lane] = __float2bfloat16(o4);
    }
}

extern "C" void kernel_launch(void* const* d_in, const int* in_sizes, int n_in,
                              void* d_out, int out_size, void* d_ws, size_t ws_size,
                              hipStream_t stream) {
    const int* users = (const int*)d_in[0];
    const int* pos   = (const int*)d_in[1];
    const int* neg   = (const int*)d_in[2];
    const int* adj_r = (const int*)d_in[3];
    const int* adj_c = (const int*)d_in[4];
    const void* adj_v = d_in[5];
    const int* ug_r  = (const int*)d_in[6];
    const int* ug_c  = (const int*)d_in[7];
    const void* ug_v = d_in[8];
    const int* ig_r  = (const int*)d_in[9];
    const int* ig_c  = (const int*)d_in[10];
    const void* ig_v = d_in[11];
    const void* ue   = d_in[12];
    const void* ie   = d_in[13];
    const void* Wgc  = d_in[14];
    const void* bgc  = d_in[15];
    const void* Wbi  = d_in[16];
    const void* bbi  = d_in[17];
    const void* Wu0  = d_in[18];
    const void* bu0  = d_in[19];
    const void* Wu1  = d_in[20];
    const void* bu1  = d_in[21];
    const void* Wi0  = d_in[22];
    const void* bi0  = d_in[23];
    const void* Wi1  = d_in[24];
    const void* bi1  = d_in[25];

    char* ws = (char*)d_ws;
    int*   FLAG = (int*)(ws + 0);                    // 256-byte slot
    float* egoA = (float*)(ws + 256);                // NTOT*64*4 = 46,080,000
    float* egoB = (float*)(ws + 256 + 46080000L);
    float* T1   = (float*)(ws + 256 + 92160000L);
    float* T2   = (float*)(ws + 256 + 138240000L);   // N_ITEM*64*4
    bf16*  UH   = (bf16*)(ws + 256 + 168960000L);    // N_USER*64*2
    bf16*  IH   = (bf16*)(ws + 256 + 176640000L);    // N_ITEM*64*2
    bf16*  NM1  = (bf16*)(ws + 256 + 192000000L);    // NTOT*64*2
    bf16*  NM2  = (bf16*)(ws + 256 + 215040000L);
    bf16*  NM3  = (bf16*)(ws + 256 + 238080000L);    // end = 261,120,256 bytes

    k_detect<<<1, 64, 0, stream>>>(adj_v, FLAG);
    k_cast2f32<<<45000, 256, 0, stream>>>(ue, ie, egoA, FLAG);

    // ---- user MLP branch ----
    hipMemsetAsync(T1, 0, (size_t)N_USER * 64 * 4, stream);
    k_spmm<<<(NNZ_UG * 16 + 255) / 256, 256, 0, stream>>>(ug_r, ug_c, ug_v, egoA, T1, NNZ_UG, FLAG);
    k_gemm64<1><<<(N_USER + 255) / 256, 256, 0, stream>>>(T1, Wu0, bu0, T2, N_USER, FLAG);
    hipMemsetAsync(T1, 0, (size_t)N_USER * 64 * 4, stream);
    k_spmm<<<(NNZ_UG * 16 + 255) / 256, 256, 0, stream>>>(ug_r, ug_c, ug_v, T2, T1, NNZ_UG, FLAG);
    k_gemm64<2><<<(N_USER + 255) / 256, 256, 0, stream>>>(T1, Wu1, bu1, UH, N_USER, FLAG);

    // ---- item MLP branch ----
    hipMemsetAsync(T1, 0, (size_t)N_ITEM * 64 * 4, stream);
    k_spmm<<<(NNZ_IG * 16 + 255) / 256, 256, 0, stream>>>(ig_r, ig_c, ig_v,
                                                          egoA + (size_t)N_USER * 64, T1, NNZ_IG, FLAG);
    k_gemm64<1><<<(N_ITEM + 255) / 256, 256, 0, stream>>>(T1, Wi0, bi0, T2, N_ITEM, FLAG);
    hipMemsetAsync(T1, 0, (size_t)N_ITEM * 64 * 4, stream);
    k_spmm<<<(NNZ_IG * 16 + 255) / 256, 256, 0, stream>>>(ig_r, ig_c, ig_v, T2, T1, NNZ_IG, FLAG);
    k_gemm64<2><<<(N_ITEM + 255) / 256, 256, 0, stream>>>(T1, Wi1, bi1, IH, N_ITEM, FLAG);

    // ---- 3 NGCF layers ----
    float* cur = egoA;
    float* nxt = egoB;
    bf16* norms[3] = {NM1, NM2, NM3};
    for (int k = 0; k < 3; k++) {
        hipMemsetAsync(T1, 0, (size_t)NTOT * 64 * 4, stream);
        k_spmm<<<(NNZ_ADJ * 16 + 255) / 256, 256, 0, stream>>>(adj_r, adj_c, adj_v, cur, T1, NNZ_ADJ, FLAG);
        k_layer<<<(NTOT + 255) / 256, 256, 0, stream>>>(T1, cur, Wgc, bgc, Wbi, bbi,
                                                        (long)k * 4096, (long)k * 64,
                                                        nxt, NTOT, FLAG);
        k_l2norm<<<45000, 256, 0, stream>>>(nxt, norms[k]);
        float* t = cur; cur = nxt; nxt = t;
    }

    // ---- output gather ----
    k_gather<<<12288, 64, 0, stream>>>(users, pos, neg, ue, ie, NM1, NM2, NM3, UH, IH,
                                       d_out, FLAG);
}

// Round 3
// 2753.845 us; speedup vs baseline: 5.3644x; 5.3644x over previous
//
#include <hip/hip_runtime.h>
#include <hip/hip_bf16.h>

#define N_USER 60000
#define N_ITEM 120000
#define NTOT   180000
#define NNZ_ADJ 3600000
#define NNZ_UG   960000
#define NNZ_IG  1920000

typedef __hip_bfloat16 bf16;

// load float element i from input tensor of unknown dtype: flag=1 -> fp32, 0 -> bf16
__device__ __forceinline__ float ldf(const void* p, long i, int f) {
    return f ? ((const float*)p)[i] : __bfloat162float(((const bf16*)p)[i]);
}

// ---------------- dtype detector (adj_vals >= 0 -> bf16 words have bit15==0) ----
__global__ void k_detect(const void* __restrict__ vals, int* __restrict__ flag) {
    if (threadIdx.x == 0 && blockIdx.x == 0) {
        const unsigned short* w = (const unsigned short*)vals;
        int cnt = 0;
        for (int i = 0; i < 512; i += 2) cnt += (w[i] >> 15) & 1;
        *flag = (cnt > 16) ? 1 : 0;
    }
}

// ---------------- cast user/item emb -> ego0 (fp32) ----------------
__global__ __launch_bounds__(256) void k_cast2f32(const void* __restrict__ ue,
                                                  const void* __restrict__ ie,
                                                  float* __restrict__ ego,
                                                  const int* __restrict__ flag) {
    int f = *flag;
    long i = (long)blockIdx.x * 256 + threadIdx.x;   // NTOT*64 = 11,520,000
    const long uN = (long)N_USER * 64;
    if (i < (long)NTOT * 64) {
        ego[i] = (i < uN) ? ldf(ue, i, f) : ldf(ie, i - uN, f);
    }
}

// ================= CSR build (counting sort by row) =================
__global__ __launch_bounds__(256) void k_hist(const int* __restrict__ rows,
                                              int* __restrict__ cnt, int nnz) {
    int e = blockIdx.x * 256 + threadIdx.x;
    if (e < nnz) atomicAdd(&cnt[rows[e]], 1);
}

__global__ __launch_bounds__(256) void k_blocksum(const int* __restrict__ cnt,
                                                  int* __restrict__ bsum, int n) {
    __shared__ int s[256];
    int i = blockIdx.x * 256 + threadIdx.x;
    s[threadIdx.x] = (i < n) ? cnt[i] : 0;
    __syncthreads();
    for (int d = 128; d >= 1; d >>= 1) {
        if (threadIdx.x < d) s[threadIdx.x] += s[threadIdx.x + d];
        __syncthreads();
    }
    if (threadIdx.x == 0) bsum[blockIdx.x] = s[0];
}

__global__ __launch_bounds__(1024) void k_scanbsum(int* __restrict__ bsum, int nb) {
    __shared__ int s[1024];
    int t = threadIdx.x;
    int v = (t < nb) ? bsum[t] : 0;
    s[t] = v;
    __syncthreads();
    for (int d = 1; d < 1024; d <<= 1) {
        int w = (t >= d) ? s[t - d] : 0;
        __syncthreads();
        if (t >= d) s[t] += w;
        __syncthreads();
    }
    if (t < nb) bsum[t] = s[t] - v;   // exclusive
}

__global__ __launch_bounds__(256) void k_scanfinal(const int* __restrict__ cnt,
                                                   const int* __restrict__ bsum,
                                                   int* __restrict__ ptr,
                                                   int* __restrict__ pos,
                                                   int n, int nnz) {
    __shared__ int s[256];
    int t = threadIdx.x;
    int i = blockIdx.x * 256 + t;
    int v = (i < n) ? cnt[i] : 0;
    s[t] = v;
    __syncthreads();
    for (int d = 1; d < 256; d <<= 1) {
        int w = (t >= d) ? s[t - d] : 0;
        __syncthreads();
        if (t >= d) s[t] += w;
        __syncthreads();
    }
    int ex = s[t] - v + bsum[blockIdx.x];
    if (i < n) { ptr[i] = ex; pos[i] = ex; }
    if (i == n) ptr[n] = nnz;
}

__global__ __launch_bounds__(256) void k_scatter(const int* __restrict__ rows,
                                                 int* __restrict__ pos,
                                                 int* __restrict__ perm, int nnz) {
    int e = blockIdx.x * 256 + threadIdx.x;
    if (e < nnz) {
        int slot = atomicAdd(&pos[rows[e]], 1);
        perm[slot] = e;
    }
}

// ================= CSR SpMM: one row per 16-lane quarter-wave =================
__global__ __launch_bounds__(256) void k_spmm_csr(const int* __restrict__ ptr,
                                                  const int* __restrict__ perm,
                                                  const int* __restrict__ cols,
                                                  const void* __restrict__ vals,
                                                  const float* __restrict__ x,
                                                  float* __restrict__ out, int n_rows,
                                                  const int* __restrict__ flag) {
    int f = *flag;
    int row = blockIdx.x * 16 + (threadIdx.x >> 4);
    int p = threadIdx.x & 15;
    if (row >= n_rows) return;
    int s = ptr[row], e = ptr[row + 1];
    float4 acc = {0.f, 0.f, 0.f, 0.f};
    for (int j = s; j < e; j++) {
        int ed = perm[j];
        float v = ldf(vals, ed, f);
        int c = cols[ed];
        const float4 xv = *(const float4*)(x + (long)c * 64 + p * 4);
        acc.x += v * xv.x;
        acc.y += v * xv.y;
        acc.z += v * xv.z;
        acc.w += v * xv.w;
    }
    *(float4*)(out + (long)row * 64 + p * 4) = acc;
}

// ---------------- Y[M,64] = act(X[M,64] @ W[64,64] + b) ----------------
// ACT: 1 = elu (f32 out), 2 = relu -> bf16 out (internal scratch)
template <int ACT>
__global__ __launch_bounds__(256) void k_gemm64(const float* __restrict__ X,
                                                const void* __restrict__ W,
                                                const void* __restrict__ b,
                                                void* __restrict__ Y, int M,
                                                const int* __restrict__ flag) {
    __shared__ float Wl[64][64];
    __shared__ float bl[64];
    int f = *flag;
    int tid = threadIdx.x;
    for (int i = tid; i < 4096; i += 256) Wl[i >> 6][i & 63] = ldf(W, i, f);
    if (tid < 64) bl[tid] = ldf(b, tid, f);
    __syncthreads();

    int r = blockIdx.x * 256 + tid;
    if (r >= M) return;
    const float* xr = X + (long)r * 64;

    float acc[64];
#pragma unroll
    for (int j = 0; j < 64; j++) acc[j] = bl[j];

    for (int k4 = 0; k4 < 64; k4 += 4) {
        float4 xv = *(const float4*)(xr + k4);
#pragma unroll
        for (int kk = 0; kk < 4; kk++) {
            float xs = (kk == 0) ? xv.x : (kk == 1) ? xv.y : (kk == 2) ? xv.z : xv.w;
#pragma unroll
            for (int j = 0; j < 64; j += 4) {
                float4 w4 = *(const float4*)&Wl[k4 + kk][j];
                acc[j + 0] += xs * w4.x;
                acc[j + 1] += xs * w4.y;
                acc[j + 2] += xs * w4.z;
                acc[j + 3] += xs * w4.w;
            }
        }
    }

    if (ACT == 2) {
        bf16* y = (bf16*)Y + (long)r * 64;
#pragma unroll
        for (int j = 0; j < 64; j++) y[j] = __float2bfloat16(fmaxf(acc[j], 0.0f));
    } else {
        float* y = (float*)Y + (long)r * 64;
#pragma unroll
        for (int j = 0; j < 64; j++) {
            float v = acc[j];
            y[j] = (v > 0.0f) ? v : (expf(v) - 1.0f);
        }
    }
}

// ---------------- fused NGCF layer transform + l2norm, ego updated IN PLACE ----
// ego = leaky_relu( S@Wgc + bgc + (ego*S)@Wbi + bbi , 0.2 );  nm = l2norm(ego) bf16
__global__ __launch_bounds__(256) void k_layer(const float* __restrict__ S,
                                               float* __restrict__ E,
                                               const void* __restrict__ Wgc,
                                               const void* __restrict__ bgc,
                                               const void* __restrict__ Wbi,
                                               const void* __restrict__ bbi,
                                               long woff, long boff,
                                               bf16* __restrict__ nm, int M,
                                               const int* __restrict__ flag) {
    __shared__ float W1[64][64];
    __shared__ float W2[64][64];
    __shared__ float bl[64];
    int f = *flag;
    int tid = threadIdx.x;
    for (int i = tid; i < 4096; i += 256) {
        W1[i >> 6][i & 63] = ldf(Wgc, woff + i, f);
        W2[i >> 6][i & 63] = ldf(Wbi, woff + i, f);
    }
    if (tid < 64) bl[tid] = ldf(bgc, boff + tid, f) + ldf(bbi, boff + tid, f);
    __syncthreads();

    int r = blockIdx.x * 256 + tid;
    if (r >= M) return;
    const float* sr = S + (long)r * 64;
    float* er = E + (long)r * 64;

    float acc[64];
#pragma unroll
    for (int j = 0; j < 64; j++) acc[j] = bl[j];

    for (int k4 = 0; k4 < 64; k4 += 4) {
        float4 sv = *(const float4*)(sr + k4);
        float4 ev = *(const float4*)(er + k4);
#pragma unroll
        for (int kk = 0; kk < 4; kk++) {
            float xs = (kk == 0) ? sv.x : (kk == 1) ? sv.y : (kk == 2) ? sv.z : sv.w;
            float xe = ((kk == 0) ? ev.x : (kk == 1) ? ev.y : (kk == 2) ? ev.z : ev.w) * xs;
#pragma unroll
            for (int j = 0; j < 64; j += 4) {
                float4 w1 = *(const float4*)&W1[k4 + kk][j];
                float4 w2 = *(const float4*)&W2[k4 + kk][j];
                acc[j + 0] += xs * w1.x + xe * w2.x;
                acc[j + 1] += xs * w1.y + xe * w2.y;
                acc[j + 2] += xs * w1.z + xe * w2.z;
                acc[j + 3] += xs * w1.w + xe * w2.w;
            }
        }
    }

    float ss = 0.0f;
#pragma unroll
    for (int j = 0; j < 64; j++) {
        float v = acc[j];
        v = (v > 0.0f) ? v : 0.2f * v;
        acc[j] = v;
        ss += v * v;
    }
    float sc = 1.0f / fmaxf(sqrtf(ss), 1e-12f);

    bf16* nr = nm + (long)r * 64;
#pragma unroll
    for (int j = 0; j < 64; j++) {
        er[j] = acc[j];
        nr[j] = __float2bfloat16(acc[j] * sc);
    }
}

// ---------------- final gather into output ----------------
__global__ __launch_bounds__(64) void k_gather(const int* __restrict__ users,
                                               const int* __restrict__ pos,
                                               const int* __restrict__ neg,
                                               const void* __restrict__ ue,
                                               const void* __restrict__ ie,
                                               const bf16* __restrict__ n1,
                                               const bf16* __restrict__ n2,
                                               const bf16* __restrict__ n3,
                                               const bf16* __restrict__ uh,
                                               const bf16* __restrict__ ih,
                                               void* __restrict__ out,
                                               const int* __restrict__ flag) {
    int f = *flag;
    int b = blockIdx.x;           // 0..12287: [users | pos | neg] x 4096
    int which = b >> 12;
    int s = b & 4095;
    int lane = threadIdx.x;       // 64
    long ebase, nbase;
    const void* e0;
    const bf16* hh;
    if (which == 0) {
        int r = users[s];
        e0 = ue; ebase = (long)r * 64;
        hh = uh + (long)r * 64;
        nbase = (long)r * 64;
    } else {
        int r = (which == 1) ? pos[s] : neg[s];
        e0 = ie; ebase = (long)r * 64;
        hh = ih + (long)r * 64;
        nbase = (long)(N_USER + r) * 64;
    }
    float o0 = ldf(e0, ebase + lane, f);
    float o1 = __bfloat162float(n1[nbase + lane]);
    float o2 = __bfloat162float(n2[nbase + lane]);
    float o3 = __bfloat162float(n3[nbase + lane]);
    float o4 = __bfloat162float(hh[lane]);
    long ob = (long)b * 320;
    if (f) {
        float* o = (float*)out + ob;
        o[lane] = o0; o[64 + lane] = o1; o[128 + lane] = o2;
        o[192 + lane] = o3; o[256 + lane] = o4;
    } else {
        bf16* o = (bf16*)out + ob;
        o[lane]       = __float2bfloat16(o0);
        o[64 + lane]  = __float2bfloat16(o1);
        o[128 + lane] = __float2bfloat16(o2);
        o[192 + lane] = __float2bfloat16(o3);
        o[256 + lane] = __float2bfloat16(o4);
    }
}

// host-side helper: build CSR for one graph
static void build_csr(const int* rows, int n, int nnz,
                      int* cnt, int* bsum, int* ptr, int* pos, int* perm,
                      hipStream_t stream) {
    int nb = (n + 255) / 256;
    hipMemsetAsync(cnt, 0, (size_t)n * 4, stream);
    k_hist<<<(nnz + 255) / 256, 256, 0, stream>>>(rows, cnt, nnz);
    k_blocksum<<<nb, 256, 0, stream>>>(cnt, bsum, n);
    k_scanbsum<<<1, 1024, 0, stream>>>(bsum, nb);
    k_scanfinal<<<(n + 1 + 255) / 256, 256, 0, stream>>>(cnt, bsum, ptr, pos, n, nnz);
    k_scatter<<<(nnz + 255) / 256, 256, 0, stream>>>(rows, pos, perm, nnz);
}

extern "C" void kernel_launch(void* const* d_in, const int* in_sizes, int n_in,
                              void* d_out, int out_size, void* d_ws, size_t ws_size,
                              hipStream_t stream) {
    const int* users = (const int*)d_in[0];
    const int* pos   = (const int*)d_in[1];
    const int* neg   = (const int*)d_in[2];
    const int* adj_r = (const int*)d_in[3];
    const int* adj_c = (const int*)d_in[4];
    const void* adj_v = d_in[5];
    const int* ug_r  = (const int*)d_in[6];
    const int* ug_c  = (const int*)d_in[7];
    const void* ug_v = d_in[8];
    const int* ig_r  = (const int*)d_in[9];
    const int* ig_c  = (const int*)d_in[10];
    const void* ig_v = d_in[11];
    const void* ue   = d_in[12];
    const void* ie   = d_in[13];
    const void* Wgc  = d_in[14];
    const void* bgc  = d_in[15];
    const void* Wbi  = d_in[16];
    const void* bbi  = d_in[17];
    const void* Wu0  = d_in[18];
    const void* bu0  = d_in[19];
    const void* Wu1  = d_in[20];
    const void* bu1  = d_in[21];
    const void* Wi0  = d_in[22];
    const void* bi0  = d_in[23];
    const void* Wi1  = d_in[24];
    const void* bi1  = d_in[25];

    char* ws = (char*)d_ws;
    int*   FLAG = (int*)(ws + 0);                        // 256 B slot
    float* egoA = (float*)(ws + 256);                    // 46,080,000
    float* T1   = (float*)(ws + 46080256L);              // 46,080,000
    float* T2   = (float*)(ws + 92160256L);              // 30,720,000
    bf16*  UH   = (bf16*)(ws + 122880256L);              //  7,680,000
    bf16*  IH   = (bf16*)(ws + 130560256L);              // 15,360,000
    bf16*  NM1  = (bf16*)(ws + 145920256L);              // 23,040,000
    bf16*  NM2  = (bf16*)(ws + 168960256L);
    bf16*  NM3  = (bf16*)(ws + 192000256L);
    int*   permA = (int*)(ws + 215040256L);              // 14,400,000
    int*   permU = (int*)(ws + 229440256L);              //  3,840,000
    int*   permI = (int*)(ws + 233280256L);              //  7,680,000
    int*   ptrA  = (int*)(ws + 240960256L);              //    720,128
    int*   ptrU  = (int*)(ws + 241680384L);              //    240,128
    int*   ptrI  = (int*)(ws + 241920512L);              //    480,128
    int*   cnt   = (int*)(ws + 242400640L);              //    720,128
    int*   posb  = (int*)(ws + 243120768L);              //    720,128
    int*   bsum  = (int*)(ws + 243840896L);              //      4,096
                                                         // end 243,844,992 (< 261 MB proven)

    k_detect<<<1, 64, 0, stream>>>(adj_v, FLAG);
    k_cast2f32<<<45000, 256, 0, stream>>>(ue, ie, egoA, FLAG);

    // ---- build CSR for the three graphs ----
    build_csr(ug_r,  N_USER, NNZ_UG,  cnt, bsum, ptrU, posb, permU, stream);
    build_csr(ig_r,  N_ITEM, NNZ_IG,  cnt, bsum, ptrI, posb, permI, stream);
    build_csr(adj_r, NTOT,   NNZ_ADJ, cnt, bsum, ptrA, posb, permA, stream);

    // ---- user MLP branch ----
    k_spmm_csr<<<(N_USER + 15) / 16, 256, 0, stream>>>(ptrU, permU, ug_c, ug_v, egoA, T1, N_USER, FLAG);
    k_gemm64<1><<<(N_USER + 255) / 256, 256, 0, stream>>>(T1, Wu0, bu0, T2, N_USER, FLAG);
    k_spmm_csr<<<(N_USER + 15) / 16, 256, 0, stream>>>(ptrU, permU, ug_c, ug_v, T2, T1, N_USER, FLAG);
    k_gemm64<2><<<(N_USER + 255) / 256, 256, 0, stream>>>(T1, Wu1, bu1, UH, N_USER, FLAG);

    // ---- item MLP branch ----
    const float* egoI = egoA + (size_t)N_USER * 64;
    k_spmm_csr<<<(N_ITEM + 15) / 16, 256, 0, stream>>>(ptrI, permI, ig_c, ig_v, egoI, T1, N_ITEM, FLAG);
    k_gemm64<1><<<(N_ITEM + 255) / 256, 256, 0, stream>>>(T1, Wi0, bi0, T2, N_ITEM, FLAG);
    k_spmm_csr<<<(N_ITEM + 15) / 16, 256, 0, stream>>>(ptrI, permI, ig_c, ig_v, T2, T1, N_ITEM, FLAG);
    k_gemm64<2><<<(N_ITEM + 255) / 256, 256, 0, stream>>>(T1, Wi1, bi1, IH, N_ITEM, FLAG);

    // ---- 3 NGCF layers (ego updated in place; norm fused) ----
    bf16* norms[3] = {NM1, NM2, NM3};
    for (int k = 0; k < 3; k++) {
        k_spmm_csr<<<(NTOT + 15) / 16, 256, 0, stream>>>(ptrA, permA, adj_c, adj_v, egoA, T1, NTOT, FLAG);
        k_layer<<<(NTOT + 255) / 256, 256, 0, stream>>>(T1, egoA, Wgc, bgc, Wbi, bbi,
                                                        (long)k * 4096, (long)k * 64,
                                                        norms[k], NTOT, FLAG);
    }

    // ---- output gather ----
    k_gather<<<12288, 64, 0, stream>>>(users, pos, neg, ue, ie, NM1, NM2, NM3, UH, IH,
                                       d_out, FLAG);
}